// Round 10
// baseline (124.128 us; speedup 1.0000x reference)
//
#include <hip/hip_runtime.h>
#include <stdint.h>

#define TT 25
#define SS 512
#define BB 4096
#define RST 36
#define IL2 1.4426950408889634f
#define LN2F 0.6931471805599453f

typedef float v2f __attribute__((ext_vector_type(2)));

__device__ __forceinline__ float ex2(float x){ return __builtin_amdgcn_exp2f(x); }
__device__ __forceinline__ float lg2(float x){ return __builtin_amdgcn_logf(x); }

// pin a value into a VGPR: opaque def, LICM can't sink/remat the producer
#define PIN(x) asm volatile("" : "+v"(x))

// row_ror:K within each 16-lane row (VALU pipe, no LDS): dst[i] = src[(i-K)&15]
template<int K>
__device__ __forceinline__ float rotk(float v){
  if constexpr (K == 0) return v;
  else return __int_as_float(__builtin_amdgcn_update_dpp(
      0, __float_as_int(v), 0x120 | K, 0xF, 0xF, true));
}

// D += broadcast(R.lo) * W   (both halves of the op read R.lo)
__device__ __forceinline__ void pkfma_lo(v2f &d, v2f r, v2f w){
  asm("v_pk_fma_f32 %0, %1, %2, %0 op_sel:[0,0,0] op_sel_hi:[0,1,1]"
      : "+v"(d) : "v"(r), "v"(w));
}
// D += broadcast(R.hi) * W
__device__ __forceinline__ void pkfma_hi(v2f &d, v2f r, v2f w){
  asm("v_pk_fma_f32 %0, %1, %2, %0 op_sel:[1,0,0] op_sel_hi:[1,1,1]"
      : "+v"(d) : "v"(r), "v"(w));
}
__device__ __forceinline__ v2f pkmul(v2f a, v2f b){
  v2f d; asm("v_pk_mul_f32 %0, %1, %2" : "=v"(d) : "v"(a), "v"(b)); return d;
}
__device__ __forceinline__ v2f pkadd(v2f a, v2f b){
  v2f d; asm("v_pk_add_f32 %0, %1, %2" : "=v"(d) : "v"(a), "v"(b)); return d;
}

#define SWZMAX(v,P) v = fmaxf(v, __int_as_float(__builtin_amdgcn_ds_swizzle(__float_as_int(v), P)))
#define SWZADD(v,P) v += __int_as_float(__builtin_amdgcn_ds_swizzle(__float_as_int(v), P))

// mask may arrive as bool(u8), int32, or float32 — detect from first element
__device__ __forceinline__ int mask_at(const void* m, int mode, int idx){
  if (mode == 1) return ((const int*)m)[idx] != 0;
  if (mode == 2) return ((const float*)m)[idx] != 0.0f;
  return ((const unsigned char*)m)[idx] != 0;
}

__global__ __launch_bounds__(256, 2)
void crf_main(const float* __restrict__ em, const float* __restrict__ startp,
              const float* __restrict__ endp, const float* __restrict__ transp,
              const int* __restrict__ labels, const void* __restrict__ maskp,
              float* __restrict__ wsr, float* __restrict__ wsl)
{
  __shared__ float smem[16 * RST];   // epilogue only
  const int tid  = threadIdx.x;
  const int w    = tid >> 6;
  const int lane = tid & 63;
  const int g    = lane >> 4;        // chain-group 0..3 within wave
  const int lidx = lane & 15;
  const int dir  = g & 1;            // 0 = forward, 1 = backward
  const int rsel = g >> 1;           // which of the wave's 2 rows
  const int row  = blockIdx.x * 8 + w * 2 + rsel;
  const int rowbase = (w * 4 + g) * RST;

  const int c1 = 2 * lidx, c2 = 2 * lidx + 1;      // adjacent col pair
  const bool v1 = (c1 < TT), v2 = (c2 < TT);
  const int c1c = v1 ? c1 : (TT - 1), c2c = v2 ? c2 : (TT - 1);
  const int cb  = (lidx < 12) ? c1 : 23;           // pair-load base col (reads cb,cb+1)
  const bool selA = (lidx < 12);                   // ev1 = selA ? x : y
  const int ws2 = (lidx <= 12) ? 2 * lidx : (26 + 2 * (lidx - 13)); // idle dump 26..31

  // --- 32-bit word-offset bases (em < 2^31 words) ---
  const int emW  = row * (SS * TT);
  const int labW = row * SS;

  // --- mask dtype detection ---
  const uint32_t w0 = ((const uint32_t*)maskp)[0];
  const int mode = (w0 == 1u) ? 1 : ((w0 == 0x3F800000u) ? 2 : 0);

  // --- lengths of the wave's two rows (2-round ballot probes) ---
  int lens[2];
  const int base2row = blockIdx.x * 8 + w * 2;
#pragma unroll
  for (int r = 0; r < 2; ++r) {
    int mb = (base2row + r) * SS;
    int pq1 = mask_at(maskp, mode, mb + lane * 8);
    unsigned long long b1 = __ballot(pq1);
    int q = __popcll(b1);
    int bs = 8 * (q - 1);
    int pq2 = mask_at(maskp, mode, mb + bs + (lane & 7));
    unsigned long long b2 = __ballot((lane < 8) && pq2);
    lens[r] = bs + __popcll(b2);
  }
  const int L = rsel ? lens[1] : lens[0];
  const int m = (L - 1) >> 1;
  const int iters = dir ? (L - 1 - m) : m;
  const int it0 = lens[0] - 1 - ((lens[0] - 1) >> 1);
  const int it1 = lens[1] - 1 - ((lens[1] - 1) >> 1);
  const int maxIters = max(it0, it1);                       // bwd >= fwd
  const int minIters = min((lens[0] - 1) >> 1, (lens[1] - 1) >> 1);  // fwd <= bwd

  // --- packed weight tables: Wt[2k]   = (E[i1->c1], E[i1->c2]),
  //                           Wt[2k+1] = (E[i2->c1], E[i2->c2]),
  //     i1=2s, i2=2s+1, s=(lidx-k)&15 (ror:k source lane). Verified mapping R6-R9.
  v2f Wt[32];
#pragma unroll
  for (int k = 0; k < 16; ++k) {
    int s  = (lidx - k) & 15;
    int i1 = 2 * s, i2 = 2 * s + 1;
    bool q1 = (i1 < TT), q2 = (i2 < TT);
    int i1c = q1 ? i1 : 0, i2c = q2 ? i2 : 0;
    float t11 = dir ? transp[c1c * TT + i1c] : transp[i1c * TT + c1c];
    float t21 = dir ? transp[c1c * TT + i2c] : transp[i2c * TT + c1c];
    float t12 = dir ? transp[c2c * TT + i1c] : transp[i1c * TT + c2c];
    float t22 = dir ? transp[c2c * TT + i2c] : transp[i2c * TT + c2c];
    Wt[2*k].x   = (q1 && v1) ? ex2(t11 * IL2) : 0.f;
    Wt[2*k].y   = (q1 && v2) ? ex2(t12 * IL2) : 0.f;
    Wt[2*k+1].x = (q2 && v1) ? ex2(t21 * IL2) : 0.f;
    Wt[2*k+1].y = (q2 && v2) ? ex2(t22 * IL2) : 0.f;
  }
#pragma unroll
  for (int k = 0; k < 32; ++k) PIN(Wt[k]);

  // --- init state pair P = (p1,p2) ---
  float pf1 = startp[c1c] + em[emW + c1c];
  float pf2 = startp[c2c] + em[emW + c2c];
  v2f P;
  P.x = v1 ? ex2((dir ? endp[c1c] : pf1) * IL2) : 0.f;
  P.y = v2 ? ex2((dir ? endp[c2c] : pf2) * IL2) : 0.f;

  // --- numerator init + label carry ---
  const int l0 = labels[labW];
  const int lE = labels[labW + L - 1];
  float num = dir ? endp[lE] : (startp[l0] + em[emW + l0]);
  int C2 = 0;
  int carry = dir ? lE : l0;

  // --- prefetch rings, depth 4 (raw values; selects/adds at consume) ---
  float emp1[4], emp2[4], tv[4], eg[4];
  int labv[4];
#pragma unroll
  for (int u = 0; u < 4; ++u) {
    int t  = dir ? (L - 1 - u) : (1 + u);       // safe: L>=256
    int o  = emW + t * TT + cb;
    emp1[u] = em[o];
    emp2[u] = em[o + 1];
    int ni = dir ? (L - 2 - u) : (1 + u);
    int nl = labels[labW + ni];
    int aL = dir ? nl : carry, bL = dir ? carry : nl;
    tv[u] = transp[aL * TT + bL];
    eg[u] = em[emW + t * TT + bL];
    carry = nl;
    labv[u] = labels[labW + (dir ? (L - 6 - u) : (5 + u))];  // labels 5..8 ahead
  }

  int emOff  = emW + (dir ? (L - 5) * TT : 5 * TT) + cb;
  int labOff = labW + (dir ? (L - 10) : 9);
  const int dstep = dir ? -TT : TT;
  const int dlab  = dir ? -1 : 1;

  int ubase = 0;

#define RK(K, D)                                                              \
    { v2f R; R.x = rotk<K>(Wv.x); R.y = rotk<K>(Wv.y);                        \
      pkfma_lo(D, R, Wt[2*(K)]);                                              \
      pkfma_hi(D, R, Wt[2*(K)+1]); }

#define STEP(u, FILL, LIVE)                                                   \
  {                                                                           \
    float ev1 = selA ? emp1[u] : emp2[u];                                     \
    v2f E; E.x = ex2(ev1 * IL2); E.y = ex2(emp2[u] * IL2);                    \
    float ta = tv[u] + eg[u];                                                 \
    bool live = true;                                                         \
    if (LIVE) { live = (ubase + (u)) < iters; num += live ? ta : 0.f; }       \
    else num += ta;                                                           \
    if (FILL) {                                                               \
      emp1[u] = em[emOff];                                                    \
      emp2[u] = em[emOff + 1];                                                \
      int nl = labv[u];                                                       \
      int aL = dir ? nl : carry, bL = dir ? carry : nl;                       \
      tv[u] = transp[aL * TT + bL];                                           \
      int ego = max(emOff + bL - cb, emW);                                    \
      eg[u] = em[ego];                                                        \
      labv[u] = labels[labOff];                                               \
      carry = nl;                                                             \
      emOff  = max(emOff + dstep, emW);                                       \
      labOff = max(labOff + dlab, labW);                                      \
    }                                                                         \
    v2f Wv = dir ? pkmul(P, E) : P;                                           \
    v2f D0 = {0.f,0.f}, D1 = {0.f,0.f}, D2 = {0.f,0.f}, D3 = {0.f,0.f};       \
    RK(0, D0)  RK(1, D1)  RK(2, D2)  RK(3, D3)                                \
    RK(4, D0)  RK(5, D1)  RK(6, D2)  RK(7, D3)                                \
    RK(8, D0)  RK(9, D1)  RK(10,D2)  RK(11,D3)                                \
    RK(12,D0)  RK(13,D1)  RK(14,D2)  RK(15,D3)                                \
    D0 = pkadd(D0, D1); D2 = pkadd(D2, D3); D0 = pkadd(D0, D2);               \
    v2f Pn = dir ? D0 : pkmul(D0, E);                                         \
    if (LIVE) { P.x = live ? Pn.x : P.x; P.y = live ? Pn.y : P.y; }           \
    else P = Pn;                                                              \
  }

#define RESCALE {                                                             \
    float mx = fmaxf(P.x, P.y);                                               \
    SWZMAX(mx, 0x041F); SWZMAX(mx, 0x081F);                                   \
    SWZMAX(mx, 0x101F); SWZMAX(mx, 0x201F);                                   \
    int ef = (__float_as_int(mx) >> 23) & 0xFF;                               \
    C2 += ef - 127;                                                           \
    float sc = __int_as_float((254 - ef) << 23);                              \
    P.x *= sc; P.y *= sc; }

  // main loop: all 4 groups live, no predication
  for (; ubase + 8 <= minIters; ubase += 8) {
    STEP(0, 1, 0) STEP(1, 1, 0) STEP(2, 1, 0) STEP(3, 1, 0)
    STEP(0, 1, 0) STEP(1, 1, 0) STEP(2, 1, 0) STEP(3, 1, 0)
    RESCALE
  }
  // band loop: predicated
  for (; ubase + 8 <= maxIters; ubase += 8) {
    STEP(0, 1, 1) STEP(1, 1, 1) STEP(2, 1, 1) STEP(3, 1, 1)
    STEP(0, 1, 1) STEP(1, 1, 1) STEP(2, 1, 1) STEP(3, 1, 1)
    RESCALE
  }
  {
    int rem = maxIters - ubase;   // 0..7; fills stay clamped-safe
    if (rem > 0) STEP(0, 1, 1)
    if (rem > 1) STEP(1, 1, 1)
    if (rem > 2) STEP(2, 1, 1)
    if (rem > 3) STEP(3, 1, 1)
    if (rem > 4) STEP(0, 0, 1)
    if (rem > 5) STEP(1, 0, 1)
    if (rem > 6) STEP(2, 0, 1)
  }
  RESCALE   // normalize before the alpha·gamma dot (avoid fp32 overflow)

#undef STEP
#undef RK
#undef RESCALE

  // --- epilogue: combine fwd (g even) with bwd partner (g^1) in-wave via LDS ---
  ((float2*)smem)[(rowbase + ws2) >> 1] = make_float2(P.x, P.y);
  smem[rowbase + 32] = num;
  smem[rowbase + 33] = __int_as_float(C2);
  // same-wave LDS ordering via lgkmcnt (no barrier needed)
  const int pbase = (w * 4 + (g ^ 1)) * RST;
  float2 qq = ((float2*)smem)[(pbase + ws2) >> 1];
  float prod = P.x * qq.x + P.y * qq.y;
  SWZADD(prod, 0x041F); SWZADD(prod, 0x081F);
  SWZADD(prod, 0x101F); SWZADD(prod, 0x201F);
  float onum = smem[pbase + 32];
  int oC2 = __float_as_int(smem[pbase + 33]);
  if (lidx == 0 && dir == 0) {
    float den = LN2F * (lg2(prod) + (float)(C2 + oC2));
    wsr[row] = (num + onum) - den;
    wsl[row] = (float)L;
  }
}

__global__ void crf_reduce(const float* __restrict__ wsr,
                           const float* __restrict__ wsl,
                           float* __restrict__ out)
{
  __shared__ float sr[256], sl[256];
  int t = threadIdx.x;
  float a = 0.0f, c = 0.0f;
  for (int i = t; i < BB; i += 256) { a += wsr[i]; c += wsl[i]; }
  sr[t] = a; sl[t] = c;
  __syncthreads();
  for (int k = 128; k > 0; k >>= 1) {
    if (t < k) { sr[t] += sr[t + k]; sl[t] += sl[t + k]; }
    __syncthreads();
  }
  if (t == 0) out[0] = sr[0] / sl[0];
}

extern "C" void kernel_launch(void* const* d_in, const int* in_sizes, int n_in,
                              void* d_out, int out_size, void* d_ws, size_t ws_size,
                              hipStream_t stream)
{
  const float* em = (const float*)d_in[0];
  const float* st = (const float*)d_in[1];
  const float* en = (const float*)d_in[2];
  const float* tr = (const float*)d_in[3];
  const int*   lb = (const int*)d_in[4];
  const void*  mk = d_in[5];
  float* wsr = (float*)d_ws;
  float* wsl = wsr + BB;
  crf_main<<<BB / 8, 256, 0, stream>>>(em, st, en, tr, lb, mk, wsr, wsl);
  crf_reduce<<<1, 256, 0, stream>>>(wsr, wsl, (float*)d_out);
}